// Round 9
// baseline (657.150 us; speedup 1.0000x reference)
//
#include <hip/hip_runtime.h>
#include <hip/hip_bf16.h>
#include <stdint.h>

typedef __bf16 bf16_t;
typedef __bf16 bf16x8 __attribute__((ext_vector_type(8)));
typedef __bf16 bf16x4 __attribute__((ext_vector_type(4)));
typedef float  f32x4  __attribute__((ext_vector_type(4)));

#define GL_LDS16(g, l)                                                         \
  __builtin_amdgcn_global_load_lds(                                            \
      (const __attribute__((address_space(1))) void*)(g),                      \
      (__attribute__((address_space(3))) void*)(l), 16, 0, 0)

#define MFMA16 __builtin_amdgcn_mfma_f32_16x16x32_bf16

#define WAITVM(N) asm volatile("s_waitcnt vmcnt(" #N ")" ::: "memory")
#define WAITLGKM asm volatile("s_waitcnt lgkmcnt(0)" ::: "memory")
#define BARRIER                                                                \
  __builtin_amdgcn_s_barrier();                                                \
  __builtin_amdgcn_sched_barrier(0)

// scores emerge from QK^T directly in exp2 domain: Q pre-scaled by this
#define SC2 0.04508422f  // (1/sqrt(1024)) * log2(e)

// shared 128x128-tile compute: reads swizzled A/B tiles, 32 MFMA
#define GCOMPUTE(APTR, BPTR)                                                    \
  { _Pragma("unroll") for (int kc = 0; kc < 2; ++kc) {                          \
      bf16x8 af[4], bfr[4];                                                     \
      _Pragma("unroll") for (int mm = 0; mm < 4; ++mm)                          \
        af[mm] = *(const bf16x8*)((APTR) + (wr * 64 + mm * 16 + lq) * 128 +     \
                                  ((kc * 64 + lg * 16) ^ rxor));                \
      _Pragma("unroll") for (int nn = 0; nn < 4; ++nn)                          \
        bfr[nn] = *(const bf16x8*)((BPTR) + (wc * 64 + nn * 16 + lq) * 128 +    \
                                   ((kc * 64 + lg * 16) ^ rxor));               \
      _Pragma("unroll") for (int mm = 0; mm < 4; ++mm)                          \
        _Pragma("unroll") for (int nn = 0; nn < 4; ++nn)                        \
          acc[mm][nn] = MFMA16(af[mm], bfr[nn], acc[mm][nn], 0, 0, 0); } }

// ---------------------------------------------------------------------------
// fp32 -> bf16 conversion of the 4 weight matrices into contiguous ws:
// order wq, wk, wv, wo. grid = 4096 x 256, 4 elems/thread.
// ---------------------------------------------------------------------------
__global__ void cvt_w_kernel(const float* __restrict__ s0, const float* __restrict__ s1,
                             const float* __restrict__ s2, const float* __restrict__ s3,
                             bf16_t* __restrict__ dst) {
  const int b = blockIdx.x;
  const float* src = (b < 1024) ? s0 : (b < 2048) ? s1 : (b < 3072) ? s2 : s3;
  const int i = ((b & 1023) * 256 + threadIdx.x) * 4;
  f32x4 v = *(const f32x4*)(src + i);
  bf16x4 w;
  w[0] = (bf16_t)v[0]; w[1] = (bf16_t)v[1]; w[2] = (bf16_t)v[2]; w[3] = (bf16_t)v[3];
  *(bf16x4*)(dst + (size_t)(b >> 10) * (1u << 20) + i) = w;
}

// ---------------------------------------------------------------------------
// Fused q/k/v projection, v3: 48KB LDS (A single + W dbuf) -> 3 blocks/CU.
// A: issue-early reg staging (2 reg buffers), swizzled ds_write after barrier.
// W: global_load_lds dbuf, XOR pre-swizzled global source, counted vmcnt(12).
// z=0 -> q (scaled SC2, [n][h][s][d]); z=1 -> k; z=2 -> v^T ([n][h][d][s]).
// ---------------------------------------------------------------------------
__global__ __launch_bounds__(256, 3) void proj_kernel(const float* __restrict__ Aq,
                                                      const float* __restrict__ Ak,
                                                      const float* __restrict__ Av,
                                                      const bf16_t* __restrict__ Wbase,
                                                      bf16_t* __restrict__ Oq,
                                                      bf16_t* __restrict__ Ok,
                                                      bf16_t* __restrict__ Ovt) {
  __shared__ char ldsA[16384];
  __shared__ char ldsB[2][16384];
  const int z  = blockIdx.z;
  const float* Af = (z == 0) ? Aq : (z == 1) ? Ak : Av;
  const bf16_t* Wptr = Wbase + ((size_t)z << 20);
  const int t  = threadIdx.x;
  const int l  = t & 63;
  const int wv = t >> 6;
  const int wr = wv >> 1, wc = wv & 1;
  const int lq = l & 15, lg = l >> 4;
  const int bid = blockIdx.x + (blockIdx.y << 6);  // 0..511
  const int pm  = (bid & 7) * 64 + (bid >> 3);     // XCD-chunked
  const int m0  = (pm >> 3) * 128;
  const int n0  = (pm & 7) * 128;

  const int ar    = t >> 4;                        // 0..15
  const int ac    = (t & 15) * 4;                  // fp32 col
  const int abyte = (t & 15) * 8;                  // A lds byte-in-row
  const int awz   = (ar & 7) << 4;                 // A write XOR
  const int wrow  = t >> 3;                        // 0..31 per it-block
  const int wcolb = ((t & 7) * 16) ^ (((t >> 3) & 7) << 4);  // W src byte-in-row
  const int rxor  = (lq & 7) << 4;                 // read-side XOR

  f32x4 acc[4][4] = {};
  f32x4 ra[8], rb[8];

#define LOADA(regs, kt)                                                         \
  { _Pragma("unroll") for (int u = 0; u < 8; ++u)                               \
      regs[u] = *(const f32x4*)(Af + (size_t)(m0 + u * 16 + ar) * 1024 +        \
                                (kt) * 64 + ac); }
#define STAGEW(buf, kt)                                                         \
  { _Pragma("unroll") for (int it = 0; it < 4; ++it) {                          \
      const int row_ = it * 32 + wrow;                                          \
      GL_LDS16(Wptr + (size_t)(n0 + row_) * 1024 + (kt) * 64 + (wcolb >> 1),    \
               ldsB[buf] + it * 4096 + t * 16); } }
#define WRITEA(regs)                                                            \
  { _Pragma("unroll") for (int u = 0; u < 8; ++u) {                             \
      bf16x4 b_;                                                                \
      b_[0] = (bf16_t)regs[u][0]; b_[1] = (bf16_t)regs[u][1];                   \
      b_[2] = (bf16_t)regs[u][2]; b_[3] = (bf16_t)regs[u][3];                   \
      *(bf16x4*)(ldsA + (u * 16 + ar) * 128 + (abyte ^ awz)) = b_; } }

  LOADA(ra, 0);
  STAGEW(0, 0);
  for (int kt = 0; kt < 16; kt += 2) {
    // phase A: tile kt from (ra, W0)
    LOADA(rb, kt + 1);
    STAGEW(1, kt + 1);
    WAITVM(12);             // ra + W0 landed; rb + W1 in flight
    WRITEA(ra);
    WAITLGKM;
    BARRIER;
    GCOMPUTE(ldsA, ldsB[0]);
    BARRIER;                // ldsA + W0 free for overwrite
    // phase B: tile kt+1 from (rb, W1)
    if (kt < 14) {
      LOADA(ra, kt + 2);
      STAGEW(0, kt + 2);
      WAITVM(12);           // rb + W1 landed
    } else {
      WAITVM(0);
    }
    WRITEA(rb);
    WAITLGKM;
    BARRIER;
    GCOMPUTE(ldsA, ldsB[1]);
    BARRIER;
  }
#undef LOADA
#undef STAGEW
#undef WRITEA

  // D frag: row = 4*lg + i, col = lq
  if (z == 2) {
#pragma unroll
    for (int mm = 0; mm < 4; ++mm)
#pragma unroll
      for (int nn = 0; nn < 4; ++nn) {
        const int r  = m0 + wr * 64 + mm * 16 + lg * 4;
        const int c  = n0 + wc * 64 + nn * 16 + lq;
        const int nb = r >> 11, s = r & 2047;
        const int hh = c >> 6, d = c & 63;
        bf16x4 w;
#pragma unroll
        for (int i = 0; i < 4; ++i) w[i] = (bf16_t)acc[mm][nn][i];
        *(bf16x4*)(Ovt + (((size_t)nb * 16 + hh) * 64 + d) * 2048 + s) = w;
      }
  } else {
    bf16_t* O      = (z == 0) ? Oq : Ok;
    const float sc = (z == 0) ? SC2 : 1.0f;
#pragma unroll
    for (int mm = 0; mm < 4; ++mm)
#pragma unroll
      for (int nn = 0; nn < 4; ++nn) {
#pragma unroll
        for (int i = 0; i < 4; ++i) {
          const int r  = m0 + wr * 64 + mm * 16 + lg * 4 + i;
          const int c  = n0 + wc * 64 + nn * 16 + lq;
          const int nb = r >> 11, s = r & 2047;
          const int hh = c >> 6, d = c & 63;
          O[(((size_t)nb * 16 + hh) * 2048 + s) * 64 + d] = (bf16_t)(acc[mm][nn][i] * sc);
        }
      }
  }
}

// ---------------------------------------------------------------------------
// Output GEMM v3: same 48KB structure. A (bf16) reg-staged issue-early with
// swizzled ds_write; W gl_lds dbuf pre-swizzled source; counted vmcnt(8).
// ---------------------------------------------------------------------------
__global__ __launch_bounds__(256, 3) void ogemm_kernel(const bf16_t* __restrict__ Ab,
                                                       const bf16_t* __restrict__ Wptr,
                                                       float* __restrict__ O) {
  __shared__ char ldsA[16384];
  __shared__ char ldsB[2][16384];
  const int t  = threadIdx.x;
  const int l  = t & 63;
  const int wv = t >> 6;
  const int wr = wv >> 1, wc = wv & 1;
  const int lq = l & 15, lg = l >> 4;
  const int bid = blockIdx.x + (blockIdx.y << 6);
  const int pm  = (bid & 7) * 64 + (bid >> 3);
  const int m0  = (pm >> 3) * 128;
  const int n0  = (pm & 7) * 128;

  const int arow  = t >> 1;                         // 0..127
  const int acb   = (t & 1) * 64;                   // byte base in 128B row
  const int awz   = (arow & 7) << 4;
  const int wrow  = t >> 3;
  const int wcolb = ((t & 7) * 16) ^ (((t >> 3) & 7) << 4);
  const int rxor  = (lq & 7) << 4;

  f32x4 acc[4][4] = {};
  bf16x8 ra[4], rb[4];

#define LOADA(regs, kt)                                                         \
  { _Pragma("unroll") for (int j = 0; j < 4; ++j)                               \
      regs[j] = *(const bf16x8*)(Ab + (size_t)(m0 + arow) * 1024 + (kt) * 64 +  \
                                 ((acb + j * 16) >> 1)); }
#define STAGEW(buf, kt)                                                         \
  { _Pragma("unroll") for (int it = 0; it < 4; ++it) {                          \
      const int row_ = it * 32 + wrow;                                          \
      GL_LDS16(Wptr + (size_t)(n0 + row_) * 1024 + (kt) * 64 + (wcolb >> 1),    \
               ldsB[buf] + it * 4096 + t * 16); } }
#define WRITEA(regs)                                                            \
  { _Pragma("unroll") for (int j = 0; j < 4; ++j)                               \
      *(bf16x8*)(ldsA + arow * 128 + ((acb + j * 16) ^ awz)) = regs[j]; }

  LOADA(ra, 0);
  STAGEW(0, 0);
  for (int kt = 0; kt < 16; kt += 2) {
    LOADA(rb, kt + 1);
    STAGEW(1, kt + 1);
    WAITVM(8);
    WRITEA(ra);
    WAITLGKM;
    BARRIER;
    GCOMPUTE(ldsA, ldsB[0]);
    BARRIER;
    if (kt < 14) {
      LOADA(ra, kt + 2);
      STAGEW(0, kt + 2);
      WAITVM(8);
    } else {
      WAITVM(0);
    }
    WRITEA(rb);
    WAITLGKM;
    BARRIER;
    GCOMPUTE(ldsA, ldsB[1]);
    BARRIER;
  }
#undef LOADA
#undef STAGEW
#undef WRITEA

#pragma unroll
  for (int mm = 0; mm < 4; ++mm)
#pragma unroll
    for (int nn = 0; nn < 4; ++nn) {
      const int r = m0 + wr * 64 + mm * 16 + lg * 4;
      const int c = n0 + wc * 64 + nn * 16 + lq;
#pragma unroll
      for (int i = 0; i < 4; ++i) O[(size_t)(r + i) * 1024 + c] = acc[mm][nn][i];
    }
}

// ---------------------------------------------------------------------------
// Flash attention (unchanged from R7's 127 us version; VALU-bound).
// ---------------------------------------------------------------------------
__device__ __forceinline__ void sm_pv(const f32x4& s0v, const f32x4& s1v, float& mrun,
                                      float& lsum, const bf16x8 vf[4], f32x4 o[4]) {
  float s[8];
#pragma unroll
  for (int i = 0; i < 4; ++i) { s[i] = s0v[i]; s[4 + i] = s1v[i]; }
  float tm = fmaxf(fmaxf(fmaxf(s[0], s[1]), fmaxf(s[2], s[3])),
                   fmaxf(fmaxf(s[4], s[5]), fmaxf(s[6], s[7])));
  if (__any(tm > mrun + 8.f)) {
    tm = fmaxf(tm, __shfl_xor(tm, 16));
    tm = fmaxf(tm, __shfl_xor(tm, 32));
    const float mnew = fmaxf(mrun, tm);
    const float corr = exp2f(mrun - mnew);
    lsum *= corr;
#pragma unroll
    for (int c = 0; c < 4; ++c)
#pragma unroll
      for (int i = 0; i < 4; ++i) o[c][i] *= corr;
    mrun = mnew;
  }
  float p[8], ps = 0.f;
#pragma unroll
  for (int j = 0; j < 8; ++j) { p[j] = exp2f(s[j] - mrun); ps += p[j]; }
  lsum += ps;
  bf16x8 pf;
#pragma unroll
  for (int j = 0; j < 8; ++j) pf[j] = (bf16_t)p[j];
  __builtin_amdgcn_s_setprio(1);
#pragma unroll
  for (int c = 0; c < 4; ++c) o[c] = MFMA16(vf[c], pf, o[c], 0, 0, 0);
  __builtin_amdgcn_s_setprio(0);
}

__global__ __launch_bounds__(256, 4) void attn_kernel(const bf16_t* __restrict__ Q,
                                                      const bf16_t* __restrict__ K,
                                                      const bf16_t* __restrict__ Vt,
                                                      bf16_t* __restrict__ AO) {
  __shared__ char ldsc[32768];
  const int t  = threadIdx.x;
  const int l  = t & 63;
  const int wv = t >> 6;
  const int lq = l & 15, lg = l >> 4;
  const int bid  = blockIdx.x;
  const int flat = (bid & 7) * 128 + (bid >> 3);
  const int qb = flat & 15, h = (flat >> 4) & 15, n = flat >> 8;
  const int s0 = qb * 128 + wv * 32;
  const size_t hoff = ((size_t)(n * 16 + h)) * 2048 * 64;
  const bf16_t* Qb  = Q + hoff;
  const bf16_t* Kb  = K + hoff;
  const bf16_t* Vtb = Vt + hoff;

  const bf16x8 qx0 = *(const bf16x8*)(Qb + (s0 + lq) * 64 + lg * 8);
  const bf16x8 qx1 = *(const bf16x8*)(Qb + (s0 + lq) * 64 + 32 + lg * 8);
  const bf16x8 qy0 = *(const bf16x8*)(Qb + (s0 + 16 + lq) * 64 + lg * 8);
  const bf16x8 qy1 = *(const bf16x8*)(Qb + (s0 + 16 + lq) * 64 + 32 + lg * 8);

  f32x4 ox[4] = {}, oy[4] = {};
  float mx = -1e30f, lx = 0.f, my = -1e30f, ly = 0.f;

  const int g1      = t >> 6;
  const int lqt     = t & 15;
  const int lgt     = (t >> 4) & 3;
  const int kperm_t = 8 * (lqt >> 2) + (lqt & 3);
  const int krow0   = (g1 >> 1) * 4 + kperm_t;
  const int kcol0   = (g1 & 1) * 32 + lgt * 8;
  const int vrow0   = 16 * g1 + lqt;
  const int vcol0   = lgt * 8;

#define STAGE(bofs, kt)                                                           \
  {                                                                               \
    const int kv0_ = (kt) * 64;                                                   \
    GL_LDS16(Kb + (size_t)(kv0_ + krow0) * 64 + kcol0, ldsc + (bofs) + t * 16);   \
    GL_LDS16(Kb + (size_t)(kv0_ + krow0 + 32) * 64 + kcol0,                       \
             ldsc + (bofs) + 4096 + t * 16);                                      \
    GL_LDS16(Vtb + (size_t)vrow0 * 2048 + kv0_ + vcol0,                           \
             ldsc + (bofs) + 8192 + t * 16);                                      \
    GL_LDS16(Vtb + (size_t)vrow0 * 2048 + kv0_ + vcol0 + 32,                      \
             ldsc + (bofs) + 12288 + t * 16);                                     \
  }
#define STEP(PB)                                                                  \
  {                                                                               \
    const char* kp_ = (const char*)ldsc + (PB) + l * 16;                          \
    const bf16x8 kf0 = *(const bf16x8*)(kp_);                                     \
    const bf16x8 kf1 = *(const bf16x8*)(kp_ + 1024);                              \
    const bf16x8 kf2 = *(const bf16x8*)(kp_ + 2048);                              \
    const bf16x8 kf3 = *(const bf16x8*)(kp_ + 3072);                              \
    bf16x8 vfr[4];                                                                \
    vfr[0] = *(const bf16x8*)(kp_ + 8192);                                        \
    vfr[1] = *(const bf16x8*)(kp_ + 9216);                                        \
    vfr[2] = *(const bf16x8*)(kp_ + 10240);                                       \
    vfr[3] = *(const bf16x8*)(kp_ + 11264);                                       \
    f32x4 zz = {};                                                                \
    __builtin_amdgcn_s_setprio(1);                                                \
    f32x4 sX0 = MFMA16(kf0, qx0, zz, 0, 0, 0);                                    \
    sX0 = MFMA16(kf1, qx1, sX0, 0, 0, 0);                                         \
    f32x4 sX1 = MFMA16(kf2, qx0, zz, 0, 0, 0);                                    \
    sX1 = MFMA16(kf3, qx1, sX1, 0, 0, 0);                                         \
    f32x4 sY0 = MFMA16(kf0, qy0, zz, 0, 0, 0);                                    \
    sY0 = MFMA16(kf1, qy1, sY0, 0, 0, 0);                                         \
    f32x4 sY1 = MFMA16(kf2, qy0, zz, 0, 0, 0);                                    \
    sY1 = MFMA16(kf3, qy1, sY1, 0, 0, 0);                                         \
    __builtin_amdgcn_s_setprio(0);                                                \
    sm_pv(sX0, sX1, mx, lx, vfr, ox);                                             \
    sm_pv(sY0, sY1, my, ly, vfr, oy);                                             \
  }

  STAGE(0, 0);
  for (int kt = 0; kt < 32; kt += 2) {
    STAGE(16384, kt + 1);
    WAITVM(4);
    BARRIER;
    STEP(0);
    STEP(4096);
    BARRIER;
    if (kt + 2 < 32) {
      STAGE(0, kt + 2);
      WAITVM(4);
    } else {
      WAITVM(0);
    }
    BARRIER;
    STEP(16384);
    STEP(16384 + 4096);
    BARRIER;
  }
#undef STAGE
#undef STEP

  lx += __shfl_xor(lx, 16); lx += __shfl_xor(lx, 32);
  ly += __shfl_xor(ly, 16); ly += __shfl_xor(ly, 32);
  const float invx = 1.f / lx;
  const float invy = 1.f / ly;
  bf16_t* AOx = AO + (((size_t)(n * 2048 + s0 + lq)) * 16 + h) * 64 + lg * 4;
  bf16_t* AOy = AO + (((size_t)(n * 2048 + s0 + 16 + lq)) * 16 + h) * 64 + lg * 4;
#pragma unroll
  for (int c = 0; c < 4; ++c) {
    bf16x4 w;
#pragma unroll
    for (int i = 0; i < 4; ++i) w[i] = (bf16_t)(ox[c][i] * invx);
    *(bf16x4*)(AOx + c * 16) = w;
#pragma unroll
    for (int i = 0; i < 4; ++i) w[i] = (bf16_t)(oy[c][i] * invy);
    *(bf16x4*)(AOy + c * 16) = w;
  }
}

// ---------------------------------------------------------------------------
extern "C" void kernel_launch(void* const* d_in, const int* in_sizes, int n_in,
                              void* d_out, int out_size, void* d_ws, size_t ws_size,
                              hipStream_t stream) {
  const float* values = (const float*)d_in[0];
  const float* keys   = (const float*)d_in[1];
  const float* query  = (const float*)d_in[2];
  const float* Wv     = (const float*)d_in[3];
  const float* Wk     = (const float*)d_in[4];
  const float* Wq     = (const float*)d_in[5];
  const float* Wo     = (const float*)d_in[6];
  float* out          = (float*)d_out;

  // ws: weights bf16 in order wq,wk,wv,wo (1M elems each), then q,k,vt,ao
  char* ws     = (char*)d_ws;
  bf16_t* w_b  = (bf16_t*)ws;
  bf16_t* wo_b = w_b + (3u << 20);
  bf16_t* q_b  = w_b + (4u << 20);
  bf16_t* k_b  = q_b + (8u << 20);
  bf16_t* vt_b = k_b + (8u << 20);
  bf16_t* ao_b = vt_b + (8u << 20);

  cvt_w_kernel<<<4096, 256, 0, stream>>>(Wq, Wk, Wv, Wo, w_b);

  proj_kernel<<<dim3(64, 8, 3), 256, 0, stream>>>(query, keys, values, w_b, q_b, k_b, vt_b);

  attn_kernel<<<1024, 256, 0, stream>>>(q_b, k_b, vt_b, ao_b);

  ogemm_kernel<<<dim3(64, 8), 256, 0, stream>>>(ao_b, wo_b, out);
}

// Round 10
// 392.163 us; speedup vs baseline: 1.6757x; 1.6757x over previous
//
#include <hip/hip_runtime.h>
#include <hip/hip_bf16.h>
#include <stdint.h>

typedef __bf16 bf16_t;
typedef __bf16 bf16x8 __attribute__((ext_vector_type(8)));
typedef __bf16 bf16x4 __attribute__((ext_vector_type(4)));
typedef float  f32x4  __attribute__((ext_vector_type(4)));

#define GL_LDS16(g, l)                                                         \
  __builtin_amdgcn_global_load_lds(                                            \
      (const __attribute__((address_space(1))) void*)(g),                      \
      (__attribute__((address_space(3))) void*)(l), 16, 0, 0)

#define MFMA16 __builtin_amdgcn_mfma_f32_16x16x32_bf16

#define WAITVM(N) asm volatile("s_waitcnt vmcnt(" #N ")" ::: "memory")
#define BARRIER                                                                \
  __builtin_amdgcn_s_barrier();                                                \
  __builtin_amdgcn_sched_barrier(0)

// scores emerge from QK^T directly in exp2 domain: Q pre-scaled by this
#define SC2 0.04508422f  // (1/sqrt(1024)) * log2(e)

// shared 128x128-tile compute: XOR-swizzled reads (rxor = (lq&7)<<4)
#define GCOMPUTE(APTR, BPTR)                                                    \
  { _Pragma("unroll") for (int kc = 0; kc < 2; ++kc) {                          \
      bf16x8 af[4], bfr[4];                                                     \
      _Pragma("unroll") for (int mm = 0; mm < 4; ++mm)                          \
        af[mm] = *(const bf16x8*)((APTR) + (wr * 64 + mm * 16 + lq) * 128 +     \
                                  ((kc * 64 + lg * 16) ^ rxor));                \
      _Pragma("unroll") for (int nn = 0; nn < 4; ++nn)                          \
        bfr[nn] = *(const bf16x8*)((BPTR) + (wc * 64 + nn * 16 + lq) * 128 +    \
                                   ((kc * 64 + lg * 16) ^ rxor));               \
      _Pragma("unroll") for (int mm = 0; mm < 4; ++mm)                          \
        _Pragma("unroll") for (int nn = 0; nn < 4; ++nn)                        \
          acc[mm][nn] = MFMA16(af[mm], bfr[nn], acc[mm][nn], 0, 0, 0); } }

// ---------------------------------------------------------------------------
// fp32 -> bf16 conversion of the 4 weight matrices into contiguous ws:
// order wq, wk, wv, wo. grid = 4096 x 256, 4 elems/thread.
// ---------------------------------------------------------------------------
__global__ void cvt_w_kernel(const float* __restrict__ s0, const float* __restrict__ s1,
                             const float* __restrict__ s2, const float* __restrict__ s3,
                             bf16_t* __restrict__ dst) {
  const int b = blockIdx.x;
  const float* src = (b < 1024) ? s0 : (b < 2048) ? s1 : (b < 3072) ? s2 : s3;
  const int i = ((b & 1023) * 256 + threadIdx.x) * 4;
  f32x4 v = *(const f32x4*)(src + i);
  bf16x4 w;
  w[0] = (bf16_t)v[0]; w[1] = (bf16_t)v[1]; w[2] = (bf16_t)v[2]; w[3] = (bf16_t)v[3];
  *(bf16x4*)(dst + (size_t)(b >> 10) * (1u << 20) + i) = w;
}

// ---------------------------------------------------------------------------
// Fused q/k/v projection, v4 = R7's 127.8us structure + both-sides XOR swizzle
// (sole delta; verified correct + conflict-eliminating in R8).
// Single-buffer LDS (32KB), __syncthreads drain loop, no launch_bounds pin.
// A (fp32): reg load -> cvt -> swizzled ds_write. W (bf16): global_load_lds
// with XOR pre-swizzled global source (LDS dest linear, m173).
// z=0 -> q (scaled SC2, [n][h][s][d]); z=1 -> k; z=2 -> v^T ([n][h][d][s]).
// ---------------------------------------------------------------------------
__global__ __launch_bounds__(256) void proj_kernel(const float* __restrict__ Aq,
                                                   const float* __restrict__ Ak,
                                                   const float* __restrict__ Av,
                                                   const bf16_t* __restrict__ Wbase,
                                                   bf16_t* __restrict__ Oq,
                                                   bf16_t* __restrict__ Ok,
                                                   bf16_t* __restrict__ Ovt) {
  __shared__ char ldsA[16384];
  __shared__ char ldsB[16384];
  const int z  = blockIdx.z;
  const float* Af = (z == 0) ? Aq : (z == 1) ? Ak : Av;
  const bf16_t* Wptr = Wbase + ((size_t)z << 20);
  const int t  = threadIdx.x;
  const int l  = t & 63;
  const int wv = t >> 6;
  const int wr = wv >> 1, wc = wv & 1;
  const int lq = l & 15, lg = l >> 4;
  const int bid = blockIdx.x + (blockIdx.y << 6);  // 0..511
  const int pm  = (bid & 7) * 64 + (bid >> 3);     // XCD-chunked
  const int m0  = (pm >> 3) * 128;
  const int n0  = (pm & 7) * 128;

  const int arow  = t >> 1;                        // 0..127 (A row)
  const int acolf = (t & 1) * 32;                  // A fp32 col base
  const int awz   = (arow & 7) << 4;               // A write XOR
  const int wcolb = ((t & 7) * 16) ^ (((t >> 3) & 7) << 4);  // W src byte
  const int rxor  = (lq & 7) << 4;                 // read XOR

  f32x4 acc[4][4] = {};

  for (int k0 = 0; k0 < 1024; k0 += 64) {
    // W tile: async direct-to-LDS, source column pre-swizzled
#pragma unroll
    for (int it = 0; it < 4; ++it) {
      const int row_ = it * 32 + (t >> 3);
      GL_LDS16(Wptr + (size_t)(n0 + row_) * 1024 + k0 + (wcolb >> 1),
               ldsB + it * 4096 + t * 16);
    }
    // A tile: fp32 load -> bf16 cvt -> swizzled ds_write
#pragma unroll
    for (int u = 0; u < 8; ++u) {
      const int colf = acolf + u * 4;
      f32x4 v = *(const f32x4*)(Af + (size_t)(m0 + arow) * 1024 + k0 + colf);
      bf16x4 b;
      b[0] = (bf16_t)v[0]; b[1] = (bf16_t)v[1]; b[2] = (bf16_t)v[2]; b[3] = (bf16_t)v[3];
      *(bf16x4*)(ldsA + arow * 128 + ((colf * 2) ^ awz)) = b;
    }
    __syncthreads();
    GCOMPUTE(ldsA, ldsB);
    __syncthreads();
  }

  // D frag: row = 4*lg + i, col = lq
  if (z == 2) {
#pragma unroll
    for (int mm = 0; mm < 4; ++mm)
#pragma unroll
      for (int nn = 0; nn < 4; ++nn) {
        const int r  = m0 + wr * 64 + mm * 16 + lg * 4;
        const int c  = n0 + wc * 64 + nn * 16 + lq;
        const int nb = r >> 11, s = r & 2047;
        const int hh = c >> 6, d = c & 63;
        bf16x4 w;
#pragma unroll
        for (int i = 0; i < 4; ++i) w[i] = (bf16_t)acc[mm][nn][i];
        *(bf16x4*)(Ovt + (((size_t)nb * 16 + hh) * 64 + d) * 2048 + s) = w;
      }
  } else {
    bf16_t* O      = (z == 0) ? Oq : Ok;
    const float sc = (z == 0) ? SC2 : 1.0f;
#pragma unroll
    for (int mm = 0; mm < 4; ++mm)
#pragma unroll
      for (int nn = 0; nn < 4; ++nn) {
#pragma unroll
        for (int i = 0; i < 4; ++i) {
          const int r  = m0 + wr * 64 + mm * 16 + lg * 4 + i;
          const int c  = n0 + wc * 64 + nn * 16 + lq;
          const int nb = r >> 11, s = r & 2047;
          const int hh = c >> 6, d = c & 63;
          O[(((size_t)nb * 16 + hh) * 2048 + s) * 64 + d] = (bf16_t)(acc[mm][nn][i] * sc);
        }
      }
  }
}

// ---------------------------------------------------------------------------
// Output GEMM v4 = R7 structure + pre-swizzled gl_lds sources + XOR'd reads.
// ---------------------------------------------------------------------------
__global__ __launch_bounds__(256) void ogemm_kernel(const bf16_t* __restrict__ Ab,
                                                    const bf16_t* __restrict__ Wptr,
                                                    float* __restrict__ O) {
  __shared__ char ldsA[16384];
  __shared__ char ldsB[16384];
  const int t  = threadIdx.x;
  const int l  = t & 63;
  const int wv = t >> 6;
  const int wr = wv >> 1, wc = wv & 1;
  const int lq = l & 15, lg = l >> 4;
  const int bid = blockIdx.x + (blockIdx.y << 6);
  const int pm  = (bid & 7) * 64 + (bid >> 3);
  const int m0  = (pm >> 3) * 128;
  const int n0  = (pm & 7) * 128;

  const int wcolb = ((t & 7) * 16) ^ (((t >> 3) & 7) << 4);
  const int rxor  = (lq & 7) << 4;

  f32x4 acc[4][4] = {};

  for (int k0 = 0; k0 < 1024; k0 += 64) {
#pragma unroll
    for (int it = 0; it < 4; ++it) {
      const int row_ = it * 32 + (t >> 3);
      GL_LDS16(Ab + (size_t)(m0 + row_) * 1024 + k0 + (wcolb >> 1),
               ldsA + it * 4096 + t * 16);
      GL_LDS16(Wptr + (size_t)(n0 + row_) * 1024 + k0 + (wcolb >> 1),
               ldsB + it * 4096 + t * 16);
    }
    __syncthreads();
    GCOMPUTE(ldsA, ldsB);
    __syncthreads();
  }

#pragma unroll
  for (int mm = 0; mm < 4; ++mm)
#pragma unroll
    for (int nn = 0; nn < 4; ++nn) {
      const int r = m0 + wr * 64 + mm * 16 + lg * 4;
      const int c = n0 + wc * 64 + nn * 16 + lq;
#pragma unroll
      for (int i = 0; i < 4; ++i) O[(size_t)(r + i) * 1024 + c] = acc[mm][nn][i];
    }
}

// ---------------------------------------------------------------------------
// Flash attention (unchanged: 127.4 us, VALU-bound).
// ---------------------------------------------------------------------------
__device__ __forceinline__ void sm_pv(const f32x4& s0v, const f32x4& s1v, float& mrun,
                                      float& lsum, const bf16x8 vf[4], f32x4 o[4]) {
  float s[8];
#pragma unroll
  for (int i = 0; i < 4; ++i) { s[i] = s0v[i]; s[4 + i] = s1v[i]; }
  float tm = fmaxf(fmaxf(fmaxf(s[0], s[1]), fmaxf(s[2], s[3])),
                   fmaxf(fmaxf(s[4], s[5]), fmaxf(s[6], s[7])));
  if (__any(tm > mrun + 8.f)) {
    tm = fmaxf(tm, __shfl_xor(tm, 16));
    tm = fmaxf(tm, __shfl_xor(tm, 32));
    const float mnew = fmaxf(mrun, tm);
    const float corr = exp2f(mrun - mnew);
    lsum *= corr;
#pragma unroll
    for (int c = 0; c < 4; ++c)
#pragma unroll
      for (int i = 0; i < 4; ++i) o[c][i] *= corr;
    mrun = mnew;
  }
  float p[8], ps = 0.f;
#pragma unroll
  for (int j = 0; j < 8; ++j) { p[j] = exp2f(s[j] - mrun); ps += p[j]; }
  lsum += ps;
  bf16x8 pf;
#pragma unroll
  for (int j = 0; j < 8; ++j) pf[j] = (bf16_t)p[j];
  __builtin_amdgcn_s_setprio(1);
#pragma unroll
  for (int c = 0; c < 4; ++c) o[c] = MFMA16(vf[c], pf, o[c], 0, 0, 0);
  __builtin_amdgcn_s_setprio(0);
}

__global__ __launch_bounds__(256, 4) void attn_kernel(const bf16_t* __restrict__ Q,
                                                      const bf16_t* __restrict__ K,
                                                      const bf16_t* __restrict__ Vt,
                                                      bf16_t* __restrict__ AO) {
  __shared__ char ldsc[32768];
  const int t  = threadIdx.x;
  const int l  = t & 63;
  const int wv = t >> 6;
  const int lq = l & 15, lg = l >> 4;
  const int bid  = blockIdx.x;
  const int flat = (bid & 7) * 128 + (bid >> 3);
  const int qb = flat & 15, h = (flat >> 4) & 15, n = flat >> 8;
  const int s0 = qb * 128 + wv * 32;
  const size_t hoff = ((size_t)(n * 16 + h)) * 2048 * 64;
  const bf16_t* Qb  = Q + hoff;
  const bf16_t* Kb  = K + hoff;
  const bf16_t* Vtb = Vt + hoff;

  const bf16x8 qx0 = *(const bf16x8*)(Qb + (s0 + lq) * 64 + lg * 8);
  const bf16x8 qx1 = *(const bf16x8*)(Qb + (s0 + lq) * 64 + 32 + lg * 8);
  const bf16x8 qy0 = *(const bf16x8*)(Qb + (s0 + 16 + lq) * 64 + lg * 8);
  const bf16x8 qy1 = *(const bf16x8*)(Qb + (s0 + 16 + lq) * 64 + 32 + lg * 8);

  f32x4 ox[4] = {}, oy[4] = {};
  float mx = -1e30f, lx = 0.f, my = -1e30f, ly = 0.f;

  const int g1      = t >> 6;
  const int lqt     = t & 15;
  const int lgt     = (t >> 4) & 3;
  const int kperm_t = 8 * (lqt >> 2) + (lqt & 3);
  const int krow0   = (g1 >> 1) * 4 + kperm_t;
  const int kcol0   = (g1 & 1) * 32 + lgt * 8;
  const int vrow0   = 16 * g1 + lqt;
  const int vcol0   = lgt * 8;

#define STAGE(bofs, kt)                                                           \
  {                                                                               \
    const int kv0_ = (kt) * 64;                                                   \
    GL_LDS16(Kb + (size_t)(kv0_ + krow0) * 64 + kcol0, ldsc + (bofs) + t * 16);   \
    GL_LDS16(Kb + (size_t)(kv0_ + krow0 + 32) * 64 + kcol0,                       \
             ldsc + (bofs) + 4096 + t * 16);                                      \
    GL_LDS16(Vtb + (size_t)vrow0 * 2048 + kv0_ + vcol0,                           \
             ldsc + (bofs) + 8192 + t * 16);                                      \
    GL_LDS16(Vtb + (size_t)vrow0 * 2048 + kv0_ + vcol0 + 32,                      \
             ldsc + (bofs) + 12288 + t * 16);                                     \
  }
#define STEP(PB)                                                                  \
  {                                                                               \
    const char* kp_ = (const char*)ldsc + (PB) + l * 16;                          \
    const bf16x8 kf0 = *(const bf16x8*)(kp_);                                     \
    const bf16x8 kf1 = *(const bf16x8*)(kp_ + 1024);                              \
    const bf16x8 kf2 = *(const bf16x8*)(kp_ + 2048);                              \
    const bf16x8 kf3 = *(const bf16x8*)(kp_ + 3072);                              \
    bf16x8 vfr[4];                                                                \
    vfr[0] = *(const bf16x8*)(kp_ + 8192);                                        \
    vfr[1] = *(const bf16x8*)(kp_ + 9216);                                        \
    vfr[2] = *(const bf16x8*)(kp_ + 10240);                                       \
    vfr[3] = *(const bf16x8*)(kp_ + 11264);                                       \
    f32x4 zz = {};                                                                \
    __builtin_amdgcn_s_setprio(1);                                                \
    f32x4 sX0 = MFMA16(kf0, qx0, zz, 0, 0, 0);                                    \
    sX0 = MFMA16(kf1, qx1, sX0, 0, 0, 0);                                         \
    f32x4 sX1 = MFMA16(kf2, qx0, zz, 0, 0, 0);                                    \
    sX1 = MFMA16(kf3, qx1, sX1, 0, 0, 0);                                         \
    f32x4 sY0 = MFMA16(kf0, qy0, zz, 0, 0, 0);                                    \
    sY0 = MFMA16(kf1, qy1, sY0, 0, 0, 0);                                         \
    f32x4 sY1 = MFMA16(kf2, qy0, zz, 0, 0, 0);                                    \
    sY1 = MFMA16(kf3, qy1, sY1, 0, 0, 0);                                         \
    __builtin_amdgcn_s_setprio(0);                                                \
    sm_pv(sX0, sX1, mx, lx, vfr, ox);                                             \
    sm_pv(sY0, sY1, my, ly, vfr, oy);                                             \
  }

  STAGE(0, 0);
  for (int kt = 0; kt < 32; kt += 2) {
    STAGE(16384, kt + 1);
    WAITVM(4);
    BARRIER;
    STEP(0);
    STEP(4096);
    BARRIER;
    if (kt + 2 < 32) {
      STAGE(0, kt + 2);
      WAITVM(4);
    } else {
      WAITVM(0);
    }
    BARRIER;
    STEP(16384);
    STEP(16384 + 4096);
    BARRIER;
  }
#undef STAGE
#undef STEP

  lx += __shfl_xor(lx, 16); lx += __shfl_xor(lx, 32);
  ly += __shfl_xor(ly, 16); ly += __shfl_xor(ly, 32);
  const float invx = 1.f / lx;
  const float invy = 1.f / ly;
  bf16_t* AOx = AO + (((size_t)(n * 2048 + s0 + lq)) * 16 + h) * 64 + lg * 4;
  bf16_t* AOy = AO + (((size_t)(n * 2048 + s0 + 16 + lq)) * 16 + h) * 64 + lg * 4;
#pragma unroll
  for (int c = 0; c < 4; ++c) {
    bf16x4 w;
#pragma unroll
    for (int i = 0; i < 4; ++i) w[i] = (bf16_t)(ox[c][i] * invx);
    *(bf16x4*)(AOx + c * 16) = w;
#pragma unroll
    for (int i = 0; i < 4; ++i) w[i] = (bf16_t)(oy[c][i] * invy);
    *(bf16x4*)(AOy + c * 16) = w;
  }
}

// ---------------------------------------------------------------------------
extern "C" void kernel_launch(void* const* d_in, const int* in_sizes, int n_in,
                              void* d_out, int out_size, void* d_ws, size_t ws_size,
                              hipStream_t stream) {
  const float* values = (const float*)d_in[0];
  const float* keys   = (const float*)d_in[1];
  const float* query  = (const float*)d_in[2];
  const float* Wv     = (const float*)d_in[3];
  const float* Wk     = (const float*)d_in[4];
  const float* Wq     = (const float*)d_in[5];
  const float* Wo     = (const float*)d_in[6];
  float* out          = (float*)d_out;

  // ws: weights bf16 in order wq,wk,wv,wo (1M elems each), then q,k,vt,ao
  char* ws     = (char*)d_ws;
  bf16_t* w_b  = (bf16_t*)ws;
  bf16_t* wo_b = w_b + (3u << 20);
  bf16_t* q_b  = w_b + (4u << 20);
  bf16_t* k_b  = q_b + (8u << 20);
  bf16_t* vt_b = k_b + (8u << 20);
  bf16_t* ao_b = vt_b + (8u << 20);

  cvt_w_kernel<<<4096, 256, 0, stream>>>(Wq, Wk, Wv, Wo, w_b);

  proj_kernel<<<dim3(64, 8, 3), 256, 0, stream>>>(query, keys, values, w_b, q_b, k_b, vt_b);

  attn_kernel<<<1024, 256, 0, stream>>>(q_b, k_b, vt_b, ao_b);

  ogemm_kernel<<<dim3(64, 8), 256, 0, stream>>>(ao_b, wo_b, out);
}